// Round 3
// baseline (839.416 us; speedup 1.0000x reference)
//
#include <hip/hip_runtime.h>
#include <math.h>

#define T_ 1024
#define D_ 3
#define H_ 64

typedef _Float16 f16x8 __attribute__((ext_vector_type(8)));
typedef float f32x4 __attribute__((ext_vector_type(4)));

__device__ __forceinline__ float sigmoid_f(float x) {
    return __builtin_amdgcn_rcpf(1.0f + __expf(-x));
}

#define MFMA(A, B, C) __builtin_amdgcn_mfma_f32_16x16x32_f16((A), (B), (C), 0, 0, 0)
// lgkm-only barrier: LDS-visibility sync without draining vmcnt (x-prefetch floats)
#define LBAR() asm volatile("s_waitcnt lgkmcnt(0)\n\ts_barrier" ::: "memory")

// Round-6: barrier-enforced ping-pong. One 512-thread block per CU holds TWO
// independent 4-wave groups (16 seq-pairs). Each GRU step splits into
//   A: ds_read h(t) + issue 9 MFMAs   (LDS + matrix pipe)
//   B: gate VALU + publish h(t+1)     (VALU pipe)
// The block barrier alternates groups A/B, so every SIMD always has one wave
// in the MFMA phase and one in the VALU phase — anti-phase by construction
// (a one-shot stagger decays; stalls attract co-resident blocks into phase).
// Barrier wait covers MFMA latency: results consumed only after next barrier.
__global__ __launch_bounds__(512, 1) void gru_mfma8(
    const float* __restrict__ x1, const float* __restrict__ x2,
    const float* __restrict__ W_ih, const float* __restrict__ W_hh,
    const float* __restrict__ b_ih, const float* __restrict__ b_hh,
    const float* __restrict__ W1, const float* __restrict__ b1,
    const float* __restrict__ W2, const float* __restrict__ b2,
    float* __restrict__ out)
{
    const int tid  = threadIdx.x;
    const int lane = tid & 63;
    const int wv   = tid >> 6;          // 0..7
    const int g    = wv >> 2;           // ping-pong group 0/1
    const int w    = wv & 3;            // wave-in-group: owns units 16w..16w+15
    const int c    = lane & 15;         // A-m / C-D col / B-n
    const int q    = lane >> 4;         // quad
    const int u    = 16 * w + c;        // this lane's hidden-unit column
    const int seq0 = blockIdx.x * 16 + g * 8;

    const float SRZ = -1.44269504f;     // -log2(e): r,z rows (exp2(-x) form)
    const float SN  =  2.88539008f;     // 2*log2(e): n rows (exp2(2x) form)
    const float gsc[3] = {SRZ, SRZ, SN};

    // ---- h-part B-fragments (scaled): wf[g][ks][j] = s_g*W_hh[g*64+u][32ks+8q+j]
    f16x8 wf[3][2];
    #pragma unroll
    for (int gg = 0; gg < 3; ++gg)
        #pragma unroll
        for (int ks = 0; ks < 2; ++ks) {
            const float* p = W_hh + (size_t)(gg * 64 + u) * H_ + 32 * ks + q * 8;
            f16x8 v;
            #pragma unroll
            for (int j = 0; j < 8; ++j) v[j] = (_Float16)(p[j] * gsc[gg]);
            wf[gg][ks] = v;
        }

    // ---- x-part B-fragments (scaled; nonzero only in q==0 lanes, j<3) ----
    f16x8 bxf[3];
    #pragma unroll
    for (int gg = 0; gg < 3; ++gg) {
        f16x8 v = {};
        if (q == 0) {
            #pragma unroll
            for (int d = 0; d < 3; ++d)
                v[d] = (_Float16)(W_ih[(size_t)(gg * 64 + u) * D_ + d] * gsc[gg]);
        }
        bxf[gg] = v;
    }

    // ---- bias C-splats (scaled) ----
    const float comb_r = (b_ih[u]      + b_hh[u])      * SRZ;
    const float comb_z = (b_ih[64 + u] + b_hh[64 + u]) * SRZ;
    const float bxn    = b_ih[128 + u] * SN;
    const float bhn    = b_hh[128 + u] * SN;
    const f32x4 Cr  = {comb_r, comb_r, comb_r, comb_r};
    const f32x4 Cz  = {comb_z, comb_z, comb_z, comb_z};
    const f32x4 Cxn = {bxn, bxn, bxn, bxn};
    const f32x4 Chn = {bhn, bhn, bhn, bhn};

    // ---- x pointer for A-frag row c (rows 0..7 = chain1, 8..15 = chain2) ----
    const float* xptr = (c < 8) ? (x1 + (size_t)(seq0 + c) * (T_ * D_))
                                : (x2 + (size_t)(seq0 + c - 8) * (T_ * D_));

    // per-group h double buffers: [group][buf][row][unit], stride 72 halves
    __shared__ alignas(16) _Float16 hb[2][2][16 * 72];
    __shared__ float dlds[2][8][68];

    float h[4];                          // rows 4q+0..3, col u
    #pragma unroll
    for (int r = 0; r < 4; ++r) h[r] = 0.f;

    // MFMA results live across one barrier (A -> B)
    f32x4 ar = {}, az = {}, axn = {}, ahn = {};

    // phase A(step s): read h(s) from hb[g][s&1], issue x- and h-MFMAs
    auto A = [&](int buf, float x0, float x1v, float x2v) {
        const f16x8 a0 = *(const f16x8*)&hb[g][buf][c * 72 + q * 8];        // k 0..31
        const f16x8 a1 = *(const f16x8*)&hb[g][buf][c * 72 + 32 + q * 8];   // k 32..63
        f16x8 ax = {};
        ax[0] = (_Float16)x0; ax[1] = (_Float16)x1v; ax[2] = (_Float16)x2v;
        ar  = MFMA(ax, bxf[0], Cr);
        az  = MFMA(ax, bxf[1], Cz);
        axn = MFMA(ax, bxf[2], Cxn);
        ar  = MFMA(a0, wf[0][0], ar);
        az  = MFMA(a0, wf[1][0], az);
        ahn = MFMA(a0, wf[2][0], Chn);
        ar  = MFMA(a1, wf[0][1], ar);
        az  = MFMA(a1, wf[1][1], az);
        ahn = MFMA(a1, wf[2][1], ahn);
    };
    // phase B(step s): gates from MFMA results, update h, publish h(s+1) -> hb[g][(s+1)&1]
    auto B = [&](int wbuf) {
        #pragma unroll
        for (int r = 0; r < 4; ++r) {
            const float eu = __builtin_amdgcn_exp2f(ar[r]);   // e^{-pre_r}
            const float ev = __builtin_amdgcn_exp2f(az[r]);   // e^{-pre_z}
            const float pu = 1.0f + eu, pv = 1.0f + ev;
            const float inv = __builtin_amdgcn_rcpf(pu * pv);
            const float rr = pv * inv;                        // sigmoid(pre_r)
            const float zz = pu * inv;                        // sigmoid(pre_z)
            const float tt = axn[r] + rr * ahn[r];            // 2log2e * pre_n
            const float e2 = __builtin_amdgcn_exp2f(tt);      // e^{2 pre_n}
            const float nn = 1.0f - 2.0f * __builtin_amdgcn_rcpf(e2 + 1.0f);
            h[r] = nn + zz * (h[r] - nn);
        }
        #pragma unroll
        for (int r = 0; r < 4; ++r)
            hb[g][wbuf][(4 * q + r) * 72 + u] = (_Float16)h[r];
    };

    // ---- prologue: publish h(0)=0, preload x, g0 runs A(0) ----
    #pragma unroll
    for (int r = 0; r < 4; ++r)
        hb[g][0][(4 * q + r) * 72 + u] = (_Float16)0.f;
    const float4* xp4 = (const float4*)xptr;
    float4 xc[3];
    #pragma unroll
    for (int i = 0; i < 3; ++i) xc[i] = xp4[i];
    LBAR();
    if (g == 0) A(0, xc[0].x, xc[0].y, xc[0].z);

    // ---- main loop: 4 steps / iteration, 8 phases, 8 barriers ----
    // pairing per barrier interval: {g0:B, g1:A} then {g0:A, g1:B} (anti-phase)
    int t = 0;
    for (; t < T_ - 4; t += 4) {
        float4 xn[3];
        const int tb = (3 * (t + 4)) / 4;
        #pragma unroll
        for (int i = 0; i < 3; ++i) xn[i] = xp4[tb + i];
        if (g == 0) {
            B(1);                                   LBAR();   // B(t)
            A(1, xc[0].w, xc[1].x, xc[1].y);        LBAR();   // A(t+1)
            B(0);                                   LBAR();   // B(t+1)
            A(0, xc[1].z, xc[1].w, xc[2].x);        LBAR();   // A(t+2)
            B(1);                                   LBAR();   // B(t+2)
            A(1, xc[2].y, xc[2].z, xc[2].w);        LBAR();   // A(t+3)
            B(0);                                   LBAR();   // B(t+3)
            A(0, xn[0].x, xn[0].y, xn[0].z);        LBAR();   // A(t+4)
        } else {
            A(0, xc[0].x, xc[0].y, xc[0].z);        LBAR();   // A(t)
            B(1);                                   LBAR();   // B(t)
            A(1, xc[0].w, xc[1].x, xc[1].y);        LBAR();   // A(t+1)
            B(0);                                   LBAR();   // B(t+1)
            A(0, xc[1].z, xc[1].w, xc[2].x);        LBAR();   // A(t+2)
            B(1);                                   LBAR();   // B(t+2)
            A(1, xc[2].y, xc[2].z, xc[2].w);        LBAR();   // A(t+3)
            B(0);                                   LBAR();   // B(t+3)
        }
        #pragma unroll
        for (int i = 0; i < 3; ++i) xc[i] = xn[i];
    }
    // ---- final 4 steps (t = T_-4): no A(T) for g0, filler barrier instead ----
    if (g == 0) {
        B(1);                                   LBAR();   // B(t)
        A(1, xc[0].w, xc[1].x, xc[1].y);        LBAR();   // A(t+1)
        B(0);                                   LBAR();   // B(t+1)
        A(0, xc[1].z, xc[1].w, xc[2].x);        LBAR();   // A(t+2)
        B(1);                                   LBAR();   // B(t+2)
        A(1, xc[2].y, xc[2].z, xc[2].w);        LBAR();   // A(t+3)
        B(0);                                   LBAR();   // B(t+3)
        LBAR();                                           // filler (match g1)
    } else {
        A(0, xc[0].x, xc[0].y, xc[0].z);        LBAR();
        B(1);                                   LBAR();
        A(1, xc[0].w, xc[1].x, xc[1].y);        LBAR();
        B(0);                                   LBAR();
        A(0, xc[1].z, xc[1].w, xc[2].x);        LBAR();
        B(1);                                   LBAR();
        A(1, xc[2].y, xc[2].z, xc[2].w);        LBAR();
        B(0);                                   LBAR();
    }

    // ---- epilogue: |h1-h2| -> Linear(64,32)+ReLU -> Linear(32,1)+sigmoid ----
    #pragma unroll
    for (int r = 0; r < 4; ++r) {
        const float o = __shfl_xor(h[r], 32);     // row m <-> m^8 (q ^= 2)
        if (q < 2) dlds[g][4 * q + r][u] = fabsf(h[r] - o);
    }
    __syncthreads();
    if (w == 0) {                      // wave 0 of each group
        const int s = lane >> 3;       // seq within group 0..7
        const int b = lane & 7;        // hidden-row group base
        float am[4];
        #pragma unroll
        for (int i = 0; i < 4; ++i) am[i] = b1[b + 8 * i];
        #pragma unroll
        for (int k4 = 0; k4 < 16; ++k4) {
            const float4 dvec = *(const float4*)&dlds[g][s][k4 * 4];
            #pragma unroll
            for (int i = 0; i < 4; ++i) {
                const float4 wv2 = *(const float4*)&W1[(b + 8 * i) * H_ + k4 * 4];
                am[i] += dvec.x * wv2.x + dvec.y * wv2.y + dvec.z * wv2.z + dvec.w * wv2.w;
            }
        }
        float part = 0.f;
        #pragma unroll
        for (int i = 0; i < 4; ++i) part += fmaxf(am[i], 0.f) * W2[b + 8 * i];
        part += __shfl_xor(part, 1);
        part += __shfl_xor(part, 2);
        part += __shfl_xor(part, 4);
        if (b == 0) out[seq0 + s] = sigmoid_f(part + b2[0]);
    }
}

extern "C" void kernel_launch(void* const* d_in, const int* in_sizes, int n_in,
                              void* d_out, int out_size, void* d_ws, size_t ws_size,
                              hipStream_t stream) {
    const float* x1   = (const float*)d_in[0];
    const float* x2   = (const float*)d_in[1];
    const float* W_ih = (const float*)d_in[2];
    const float* W_hh = (const float*)d_in[3];
    const float* b_ih = (const float*)d_in[4];
    const float* b_hh = (const float*)d_in[5];
    const float* W1   = (const float*)d_in[6];
    const float* b1   = (const float*)d_in[7];
    const float* W2   = (const float*)d_in[8];
    const float* b2   = (const float*)d_in[9];

    const int B = in_sizes[0] / (T_ * D_);      // 4096
    dim3 grid(B / 16), block(512);
    gru_mfma8<<<grid, block, 0, stream>>>(x1, x2, W_ih, W_hh, b_ih, b_hh,
                                          W1, b1, W2, b2, (float*)d_out);
}

// Round 4
// 644.170 us; speedup vs baseline: 1.3031x; 1.3031x over previous
//
#include <hip/hip_runtime.h>
#include <math.h>

#define T_ 1024
#define D_ 3
#define H_ 64
#define LDH 76   // h-tile LDS stride (halves): 38 dwords, breaks c/c+8 bank aliasing

typedef _Float16 f16x8 __attribute__((ext_vector_type(8)));
typedef float f32x4 __attribute__((ext_vector_type(4)));

__device__ __forceinline__ float sigmoid_f(float x) {
    return __builtin_amdgcn_rcpf(1.0f + __expf(-x));
}

#define MFMA(A, B, C) __builtin_amdgcn_mfma_f32_16x16x32_f16((A), (B), (C), 0, 0, 0)
// lgkm-only barrier: LDS visibility without draining vmcnt (x-prefetch floats)
#define LBAR() asm volatile("s_waitcnt lgkmcnt(0)\n\ts_barrier" ::: "memory")

// Round-7: R0 skeleton (512 blocks x 4 waves, 1 barrier/step) + latency diet:
//  (1) x-MFMAs software-pipelined one step ahead: issued post-barrier in the
//      ds_read shadow (accumulators in 2 alternating reg sets, static unroll).
//      ax build stays pre-barrier covering publish-write settle. Bit-identical
//      accumulation order (x-part -> a0 -> a1).
//  (2) 8-step unroll, two x-prefetch buffers, fixed refill points (no rotate
//      movs); vmcnt floats across the lgkm-only barriers (true async prefetch).
//  (3) LDS stride 72->76 halves: kills lane c / c+8 bank aliasing on b128 reads.
//  (4) setprio(1) over the post-barrier read+MFMA critical section.
__global__ __launch_bounds__(256, 2) void gru_mfma9(
    const float* __restrict__ x1, const float* __restrict__ x2,
    const float* __restrict__ W_ih, const float* __restrict__ W_hh,
    const float* __restrict__ b_ih, const float* __restrict__ b_hh,
    const float* __restrict__ W1, const float* __restrict__ b1,
    const float* __restrict__ W2, const float* __restrict__ b2,
    float* __restrict__ out)
{
    const int lane = threadIdx.x & 63;
    const int w    = threadIdx.x >> 6;   // wave 0..3: owns units 16w..16w+15
    const int c    = lane & 15;          // A-m / C-D col / B-n
    const int q    = lane >> 4;          // quad
    const int u    = 16 * w + c;         // this lane's hidden-unit column
    const int seq0 = blockIdx.x * 8;

    const float SRZ = -1.44269504f;      // -log2(e): r,z rows (exp2(-x) form)
    const float SN  =  2.88539008f;      // 2*log2(e): n rows (exp2(2x) form)
    const float gsc[3] = {SRZ, SRZ, SN};

    // ---- h-part B-fragments (scaled): wf[g][ks][j] = s_g*W_hh[g*64+u][32ks+8q+j]
    f16x8 wf[3][2];
    #pragma unroll
    for (int g = 0; g < 3; ++g)
        #pragma unroll
        for (int ks = 0; ks < 2; ++ks) {
            const float* p = W_hh + (size_t)(g * 64 + u) * H_ + 32 * ks + q * 8;
            f16x8 v;
            #pragma unroll
            for (int j = 0; j < 8; ++j) v[j] = (_Float16)(p[j] * gsc[g]);
            wf[g][ks] = v;
        }

    // ---- x-part B-fragments (scaled; nonzero only in q==0 lanes, j<3) ----
    f16x8 bxf[3];
    #pragma unroll
    for (int g = 0; g < 3; ++g) {
        f16x8 v = {};
        if (q == 0) {
            #pragma unroll
            for (int d = 0; d < 3; ++d)
                v[d] = (_Float16)(W_ih[(size_t)(g * 64 + u) * D_ + d] * gsc[g]);
        }
        bxf[g] = v;
    }

    // ---- bias C-splats (scaled) ----
    const float comb_r = (b_ih[u]      + b_hh[u])      * SRZ;
    const float comb_z = (b_ih[64 + u] + b_hh[64 + u]) * SRZ;
    const float bxn    = b_ih[128 + u] * SN;
    const float bhn    = b_hh[128 + u] * SN;
    const f32x4 Cr  = {comb_r, comb_r, comb_r, comb_r};
    const f32x4 Cz  = {comb_z, comb_z, comb_z, comb_z};
    const f32x4 Cxn = {bxn, bxn, bxn, bxn};
    const f32x4 Chn = {bhn, bhn, bhn, bhn};

    // ---- x pointer for A-frag row c (rows 0..7 = chain1, 8..15 = chain2) ----
    const float* xptr = (c < 8) ? (x1 + (size_t)(seq0 + c) * (T_ * D_))
                                : (x2 + (size_t)(seq0 + c - 8) * (T_ * D_));

    // h-tile double buffer: [row][unit], stride LDH halves
    __shared__ alignas(16) _Float16 hb[2][16 * LDH];
    __shared__ float dlds[8][68];

    float h[4];                          // rows 4q+0..3, col u
    #pragma unroll
    for (int r = 0; r < 4; ++r) h[r] = 0.f;

    // step t: publish h(t), barrier, read h-tile, x-MFMAs for t+1 (into xnxt)
    // in the ds_read shadow, h-MFMAs for t onto xcur, gates -> h(t+1).
    auto step = [&](int buf, float nx0, float nx1, float nx2,
                    f32x4 (&xcur)[3], f32x4 (&xnxt)[3]) {
        #pragma unroll
        for (int r = 0; r < 4; ++r)
            hb[buf][(4 * q + r) * LDH + u] = (_Float16)h[r];
        // build ax(t+1) pre-barrier (covers write settle)
        f16x8 ax = {};
        ax[0] = (_Float16)nx0; ax[1] = (_Float16)nx1; ax[2] = (_Float16)nx2;
        LBAR();
        __builtin_amdgcn_s_setprio(1);
        const f16x8 a0 = *(const f16x8*)&hb[buf][c * LDH + q * 8];        // k 0..31
        const f16x8 a1 = *(const f16x8*)&hb[buf][c * LDH + 32 + q * 8];   // k 32..63
        // next step's x-MFMAs fill the ds_read latency window
        xnxt[0] = MFMA(ax, bxf[0], Cr);
        xnxt[1] = MFMA(ax, bxf[1], Cz);
        xnxt[2] = MFMA(ax, bxf[2], Cxn);
        f32x4 ar  = MFMA(a0, wf[0][0], xcur[0]);
        f32x4 az  = MFMA(a0, wf[1][0], xcur[1]);
        f32x4 ahn = MFMA(a0, wf[2][0], Chn);
        ar  = MFMA(a1, wf[0][1], ar);
        az  = MFMA(a1, wf[1][1], az);
        ahn = MFMA(a1, wf[2][1], ahn);
        __builtin_amdgcn_s_setprio(0);
        const f32x4 axn = xcur[2];

        #pragma unroll
        for (int r = 0; r < 4; ++r) {
            const float eu = __builtin_amdgcn_exp2f(ar[r]);   // e^{-pre_r}
            const float ev = __builtin_amdgcn_exp2f(az[r]);   // e^{-pre_z}
            const float pu = 1.0f + eu, pv = 1.0f + ev;
            const float inv = __builtin_amdgcn_rcpf(pu * pv);
            const float rr = pv * inv;                        // sigmoid(pre_r)
            const float zz = pu * inv;                        // sigmoid(pre_z)
            const float tt = axn[r] + rr * ahn[r];            // 2log2e * pre_n
            const float e2 = __builtin_amdgcn_exp2f(tt);      // e^{2 pre_n}
            const float nn = 1.0f - 2.0f * __builtin_amdgcn_rcpf(e2 + 1.0f);
            h[r] = nn + zz * (h[r] - nn);
        }
    };

    // ---- x prefetch: 2 buffers of 4 steps each, distance >= 4 steps ----
    const float4* xp4 = (const float4*)xptr;
    float4 xc[3], xd[3];
    #pragma unroll
    for (int i = 0; i < 3; ++i) xc[i] = xp4[i];       // steps t..t+3
    #pragma unroll
    for (int i = 0; i < 3; ++i) xd[i] = xp4[3 + i];   // steps t+4..t+7

    // x-part accumulators for step 0
    f32x4 xpA[3], xpB[3];
    {
        f16x8 ax = {};
        ax[0] = (_Float16)xc[0].x; ax[1] = (_Float16)xc[0].y; ax[2] = (_Float16)xc[0].z;
        xpA[0] = MFMA(ax, bxf[0], Cr);
        xpA[1] = MFMA(ax, bxf[1], Cz);
        xpA[2] = MFMA(ax, bxf[2], Cxn);
    }

    for (int t = 0; t < T_; t += 8) {
        step(0, xc[0].w, xc[1].x, xc[1].y, xpA, xpB);   // t   ; next=t+1
        step(1, xc[1].z, xc[1].w, xc[2].x, xpB, xpA);   // t+1 ; next=t+2
        step(0, xc[2].y, xc[2].z, xc[2].w, xpA, xpB);   // t+2 ; next=t+3
        {   // refill xc <- steps t+8..t+11 (consumed from step t+7 onward)
            const int tb = (t + 8 < T_) ? (3 * (t + 8)) / 4 : (3 * t) / 4;
            #pragma unroll
            for (int i = 0; i < 3; ++i) xc[i] = xp4[tb + i];
        }
        step(1, xd[0].x, xd[0].y, xd[0].z, xpB, xpA);   // t+3 ; next=t+4
        step(0, xd[0].w, xd[1].x, xd[1].y, xpA, xpB);   // t+4 ; next=t+5
        step(1, xd[1].z, xd[1].w, xd[2].x, xpB, xpA);   // t+5 ; next=t+6
        step(0, xd[2].y, xd[2].z, xd[2].w, xpA, xpB);   // t+6 ; next=t+7
        {   // refill xd <- steps t+12..t+15 (consumed from step t+11 onward)
            const int tb = (t + 12 < T_) ? (3 * (t + 12)) / 4 : (3 * t) / 4;
            #pragma unroll
            for (int i = 0; i < 3; ++i) xd[i] = xp4[tb + i];
        }
        step(1, xc[0].x, xc[0].y, xc[0].z, xpB, xpA);   // t+7 ; next=t+8 (new xc)
    }

    // ---- epilogue: |h1-h2| -> Linear(64,32)+ReLU -> Linear(32,1)+sigmoid ----
    #pragma unroll
    for (int r = 0; r < 4; ++r) {
        const float o = __shfl_xor(h[r], 32);     // row m <-> m^8 (q ^= 2)
        if (q < 2) dlds[4 * q + r][u] = fabsf(h[r] - o);
    }
    __syncthreads();
    if (w == 0) {
        const int s = lane >> 3;   // seq within block 0..7
        const int b = lane & 7;    // hidden-row group base
        float am[4];
        #pragma unroll
        for (int i = 0; i < 4; ++i) am[i] = b1[b + 8 * i];
        #pragma unroll
        for (int k4 = 0; k4 < 16; ++k4) {
            const float4 dvec = *(const float4*)&dlds[s][k4 * 4];
            #pragma unroll
            for (int i = 0; i < 4; ++i) {
                const float4 wv = *(const float4*)&W1[(b + 8 * i) * H_ + k4 * 4];
                am[i] += dvec.x * wv.x + dvec.y * wv.y + dvec.z * wv.z + dvec.w * wv.w;
            }
        }
        float part = 0.f;
        #pragma unroll
        for (int i = 0; i < 4; ++i) part += fmaxf(am[i], 0.f) * W2[b + 8 * i];
        part += __shfl_xor(part, 1);
        part += __shfl_xor(part, 2);
        part += __shfl_xor(part, 4);
        if (b == 0) out[seq0 + s] = sigmoid_f(part + b2[0]);
    }
}

extern "C" void kernel_launch(void* const* d_in, const int* in_sizes, int n_in,
                              void* d_out, int out_size, void* d_ws, size_t ws_size,
                              hipStream_t stream) {
    const float* x1   = (const float*)d_in[0];
    const float* x2   = (const float*)d_in[1];
    const float* W_ih = (const float*)d_in[2];
    const float* W_hh = (const float*)d_in[3];
    const float* b_ih = (const float*)d_in[4];
    const float* b_hh = (const float*)d_in[5];
    const float* W1   = (const float*)d_in[6];
    const float* b1   = (const float*)d_in[7];
    const float* W2   = (const float*)d_in[8];
    const float* b2   = (const float*)d_in[9];

    const int B = in_sizes[0] / (T_ * D_);      // 4096
    dim3 grid(B / 8), block(256);
    gru_mfma9<<<grid, block, 0, stream>>>(x1, x2, W_ih, W_hh, b_ih, b_hh,
                                          W1, b1, W2, b2, (float*)d_out);
}

// Round 5
// 546.653 us; speedup vs baseline: 1.5356x; 1.1784x over previous
//
#include <hip/hip_runtime.h>
#include <math.h>

#define T_ 1024
#define D_ 3
#define H_ 64

typedef _Float16 f16x8 __attribute__((ext_vector_type(8)));
typedef _Float16 f16x4 __attribute__((ext_vector_type(4)));
typedef float f32x4 __attribute__((ext_vector_type(4)));

__device__ __forceinline__ float sigmoid_f(float x) {
    return __builtin_amdgcn_rcpf(1.0f + __expf(-x));
}

#define MFMA(A, B, C) __builtin_amdgcn_mfma_f32_16x16x32_f16((A), (B), (C), 0, 0, 0)

// Round-8: R0 skeleton (512 blocks x 4 waves, __syncthreads, pre-barrier
// x-MFMAs, 4-step unroll, stride 72) + ONE change: transposed MFMA
// (preact^T[unit,seq] = MFMA(A=W_frag, B=h_frag^T)). A/B frags share the same
// per-lane mapping, so W fragments are unchanged; the D-layout now gives each
// lane 4 CONSECUTIVE units for one seq -> h publish is a single ds_write_b64
// (was 4 scattered ds_write_u16), shrinking the pre-barrier lgkm drain.
// B-frag h reads stay 2x ds_read_b128. Bit-identical accumulation order.
__global__ __launch_bounds__(256, 2) void gru_mfma10(
    const float* __restrict__ x1, const float* __restrict__ x2,
    const float* __restrict__ W_ih, const float* __restrict__ W_hh,
    const float* __restrict__ b_ih, const float* __restrict__ b_hh,
    const float* __restrict__ W1, const float* __restrict__ b1,
    const float* __restrict__ W2, const float* __restrict__ b2,
    float* __restrict__ out)
{
    const int lane = threadIdx.x & 63;
    const int w    = threadIdx.x >> 6;   // wave 0..3: owns units 16w..16w+15
    const int c    = lane & 15;          // A row (unit_out) / B-D col (seq)
    const int q    = lane >> 4;          // quad
    const int u    = 16 * w + c;         // A-side unit_out for W fragments
    const int u2   = 16 * w + 4 * q;     // D-side unit_out base (rows 4q+r)
    const int seq0 = blockIdx.x * 8;

    const float SRZ = -1.44269504f;      // -log2(e): r,z rows (exp2(-x) form)
    const float SN  =  2.88539008f;      // 2*log2(e): n rows (exp2(2x) form)
    const float gsc[3] = {SRZ, SRZ, SN};

    // ---- W_hh A-fragments (scaled) — identical registers to R0's B-frags:
    // wf[g][ks][j] = s_g * W_hh[g*64+u][32ks+8q+j]
    f16x8 wf[3][2];
    #pragma unroll
    for (int g = 0; g < 3; ++g)
        #pragma unroll
        for (int ks = 0; ks < 2; ++ks) {
            const float* p = W_hh + (size_t)(g * 64 + u) * H_ + 32 * ks + q * 8;
            f16x8 v;
            #pragma unroll
            for (int j = 0; j < 8; ++j) v[j] = (_Float16)(p[j] * gsc[g]);
            wf[g][ks] = v;
        }

    // ---- W_ih A-fragments (scaled; nonzero only in q==0 lanes, j<3) ----
    f16x8 axf[3];
    #pragma unroll
    for (int g = 0; g < 3; ++g) {
        f16x8 v = {};
        if (q == 0) {
            #pragma unroll
            for (int d = 0; d < 3; ++d)
                v[d] = (_Float16)(W_ih[(size_t)(g * 64 + u) * D_ + d] * gsc[g]);
        }
        axf[g] = v;
    }

    // ---- bias C vectors (scaled), per D-row r: unit u2+r ----
    f32x4 Cr, Cz, Cxn, Chn;
    #pragma unroll
    for (int r = 0; r < 4; ++r) {
        Cr[r]  = (b_ih[u2 + r]       + b_hh[u2 + r])       * SRZ;
        Cz[r]  = (b_ih[64 + u2 + r]  + b_hh[64 + u2 + r])  * SRZ;
        Cxn[r] = b_ih[128 + u2 + r] * SN;
        Chn[r] = b_hh[128 + u2 + r] * SN;
    }

    // ---- x pointer for B-frag col c (seqs 0..7 = chain1, 8..15 = chain2) ----
    const float* xptr = (c < 8) ? (x1 + (size_t)(seq0 + c) * (T_ * D_))
                                : (x2 + (size_t)(seq0 + c - 8) * (T_ * D_));

    // h-tile double buffer: [seq][unit], stride 72 halves
    __shared__ alignas(16) _Float16 hb[2][16 * 72];
    __shared__ float dlds[8][68];

    float h[4];                          // units u2+0..3, seq c
    #pragma unroll
    for (int r = 0; r < 4; ++r) h[r] = 0.f;

    auto step = [&](int buf, float x0, float x1v, float x2v) {
        // publish h(t): ONE contiguous b64 write (units u2..u2+3 of seq c)
        f16x4 hp;
        #pragma unroll
        for (int r = 0; r < 4; ++r) hp[r] = (_Float16)h[r];
        *(f16x4*)&hb[buf][c * 72 + u2] = hp;
        // x-part MFMAs: independent of h(t), fill the pre-barrier gap.
        // bx junk lanes are harmless: axf is zero wherever bx is junk.
        f16x8 bx = {};
        bx[0] = (_Float16)x0; bx[1] = (_Float16)x1v; bx[2] = (_Float16)x2v;
        f32x4 ar  = MFMA(axf[0], bx, Cr);
        f32x4 az  = MFMA(axf[1], bx, Cz);
        f32x4 axn = MFMA(axf[2], bx, Cxn);
        __syncthreads();
        const f16x8 b0 = *(const f16x8*)&hb[buf][c * 72 + q * 8];        // units 0..31
        const f16x8 b1 = *(const f16x8*)&hb[buf][c * 72 + 32 + q * 8];   // units 32..63

        ar  = MFMA(wf[0][0], b0, ar);
        az  = MFMA(wf[1][0], b0, az);
        f32x4 ahn = MFMA(wf[2][0], b0, Chn);
        ar  = MFMA(wf[0][1], b1, ar);
        az  = MFMA(wf[1][1], b1, az);
        ahn = MFMA(wf[2][1], b1, ahn);

        // gates: ar,az hold -log2e*preact; axn,ahn hold 2log2e*parts
        #pragma unroll
        for (int r = 0; r < 4; ++r) {
            const float eu = __builtin_amdgcn_exp2f(ar[r]);   // e^{-pre_r}
            const float ev = __builtin_amdgcn_exp2f(az[r]);   // e^{-pre_z}
            const float pu = 1.0f + eu, pv = 1.0f + ev;
            const float inv = __builtin_amdgcn_rcpf(pu * pv);
            const float rr = pv * inv;                        // sigmoid(pre_r)
            const float zz = pu * inv;                        // sigmoid(pre_z)
            const float tt = axn[r] + rr * ahn[r];            // 2log2e * pre_n
            const float e2 = __builtin_amdgcn_exp2f(tt);      // e^{2 pre_n}
            const float nn = 1.0f - 2.0f * __builtin_amdgcn_rcpf(e2 + 1.0f);
            h[r] = nn + zz * (h[r] - nn);
        }
    };

    // x batched: float4 x3 = 12 floats = 4 steps; prefetch distance 4 steps
    const float4* xp4 = (const float4*)xptr;
    float4 xc[3];
    #pragma unroll
    for (int i = 0; i < 3; ++i) xc[i] = xp4[i];

    for (int t = 0; t < T_; t += 4) {
        float4 xn[3];
        const int tb = (t + 4 < T_) ? (3 * (t + 4)) / 4 : (3 * t) / 4;
        #pragma unroll
        for (int i = 0; i < 3; ++i) xn[i] = xp4[tb + i];
        step(0, xc[0].x, xc[0].y, xc[0].z);
        step(1, xc[0].w, xc[1].x, xc[1].y);
        step(0, xc[1].z, xc[1].w, xc[2].x);
        step(1, xc[2].y, xc[2].z, xc[2].w);
        #pragma unroll
        for (int i = 0; i < 3; ++i) xc[i] = xn[i];
    }

    // ---- epilogue: |h1-h2| -> Linear(64,32)+ReLU -> Linear(32,1)+sigmoid ----
    // lane holds h_last[seq c][units u2+0..3]; pair seq c <-> c^8 is lane^8.
    {
        float d4[4];
        #pragma unroll
        for (int r = 0; r < 4; ++r) {
            const float o = __shfl_xor(h[r], 8);
            d4[r] = fabsf(h[r] - o);
        }
        if (c < 8) {
            float4 v = {d4[0], d4[1], d4[2], d4[3]};
            *(float4*)&dlds[c][u2] = v;          // units u2..u2+3, contiguous
        }
    }
    __syncthreads();
    if (w == 0) {
        const int s = lane >> 3;   // seq within block 0..7
        const int b = lane & 7;    // hidden-row group base
        float am[4];
        #pragma unroll
        for (int i = 0; i < 4; ++i) am[i] = b1[b + 8 * i];
        #pragma unroll
        for (int k4 = 0; k4 < 16; ++k4) {
            const float4 dvec = *(const float4*)&dlds[s][k4 * 4];
            #pragma unroll
            for (int i = 0; i < 4; ++i) {
                const float4 wv = *(const float4*)&W1[(b + 8 * i) * H_ + k4 * 4];
                am[i] += dvec.x * wv.x + dvec.y * wv.y + dvec.z * wv.z + dvec.w * wv.w;
            }
        }
        float part = 0.f;
        #pragma unroll
        for (int i = 0; i < 4; ++i) part += fmaxf(am[i], 0.f) * W2[b + 8 * i];
        part += __shfl_xor(part, 1);
        part += __shfl_xor(part, 2);
        part += __shfl_xor(part, 4);
        if (b == 0) out[seq0 + s] = sigmoid_f(part + b2[0]);
    }
}

extern "C" void kernel_launch(void* const* d_in, const int* in_sizes, int n_in,
                              void* d_out, int out_size, void* d_ws, size_t ws_size,
                              hipStream_t stream) {
    const float* x1   = (const float*)d_in[0];
    const float* x2   = (const float*)d_in[1];
    const float* W_ih = (const float*)d_in[2];
    const float* W_hh = (const float*)d_in[3];
    const float* b_ih = (const float*)d_in[4];
    const float* b_hh = (const float*)d_in[5];
    const float* W1   = (const float*)d_in[6];
    const float* b1   = (const float*)d_in[7];
    const float* W2   = (const float*)d_in[8];
    const float* b2   = (const float*)d_in[9];

    const int B = in_sizes[0] / (T_ * D_);      // 4096
    dim3 grid(B / 8), block(256);
    gru_mfma10<<<grid, block, 0, stream>>>(x1, x2, W_ih, W_hh, b_ih, b_hh,
                                           W1, b1, W2, b2, (float*)d_out);
}